// Round 12
// baseline (659.208 us; speedup 1.0000x reference)
//
#include <hip/hip_runtime.h>
#include <hip/hip_bf16.h>

// Sizes: N=100000, E=1600000, B=128, F=128, H=64.
// sigmoid(<e@Wk+bk, q_g>) = sigmoid(e . (Wk q_g) + bk.q_g)
//   => per-graph v[g] (128 floats) + scalar c[g].
//
// R10 -> R11: (a) final GEMM fused into agg via last-block pattern
// (threadfence + per-graph done counter; winner re-reads e_agg with
// device-scope atomic loads -> safe across per-XCD L2s) -- kills a launch;
// (b) SLICES 16->32 for finer tail granularity.

#define FDIM 128
#define BGRAPH 128
#define HDIM 64
#define SLICES 32
#define CAP 16384
#define CURSOR_STRIDE 16
#define SC_THREADS 512
#define SC_ITEMS 16          // 512*16 = 8192 edges per block
#define SC_TOTAL (SC_THREADS * SC_ITEMS)
#define MAXCHUNK (CAP / SLICES)   // 512

typedef float vf4 __attribute__((ext_vector_type(4)));

__device__ inline vf4 ldnt4(const float* p) {
    return __builtin_nontemporal_load(reinterpret_cast<const vf4*>(p));
}

// ------- prep: edge binning blocks + (precompute + node agg) blocks --------
__global__ __launch_bounds__(SC_THREADS) void prep_kernel(
    const int* __restrict__ src, const int* __restrict__ batch,
    int* __restrict__ cursor,     // [B*CURSOR_STRIDE], pre-zeroed
    int* __restrict__ order,      // [B*CAP]
    float* __restrict__ x_agg,    // [B,128] pre-zeroed, atomically accumulated
    const float* __restrict__ x,  // [N,128]
    const float* __restrict__ u,
    const float* __restrict__ Wk_e, const float* __restrict__ bk_e,
    const float* __restrict__ Wq_e, const float* __restrict__ bq_e,
    const float* __restrict__ Wk_x, const float* __restrict__ bk_x,
    const float* __restrict__ Wq_x, const float* __restrict__ bq_x,
    float* __restrict__ v_e, float* __restrict__ c_e,
    int E, int N, int nb_edge)
{
    const int t = threadIdx.x;

    if (blockIdx.x < nb_edge) {
        // ------- edge binning: gid+rank -> LDS counting sort -> coalesced out ---
        __shared__ int lh[BGRAPH];            // counts
        __shared__ int s_lofs[BGRAPH];        // local exclusive offsets
        __shared__ int s_gbase[BGRAPH];       // g*CAP + gbase - lofs
        __shared__ int wtot[2];
        __shared__ int s_ids[SC_TOTAL];       // 32 KB grouped edge ids
        __shared__ unsigned char s_bin[SC_TOTAL]; // 8 KB bin tag per slot

        if (t < BGRAPH) lh[t] = 0;
        __syncthreads();

        const int base0 = blockIdx.x * SC_TOTAL;
        const int nval_blk = min(SC_TOTAL, E - base0);

        // phase 1a: src loads (independent)
        int iv[SC_ITEMS];
#pragma unroll
        for (int k = 0; k < SC_ITEMS; ++k) {
            const int i = base0 + k * SC_THREADS + t;
            iv[k] = (i < E) ? __builtin_nontemporal_load(src + i) : -1;
        }
        // phase 1b: batch gathers (independent; batch is L2-hot 400 KB)
        int gv[SC_ITEMS];
#pragma unroll
        for (int k = 0; k < SC_ITEMS; ++k)
            gv[k] = (iv[k] >= 0) ? batch[iv[k]] : -1;
        // phase 1c: rank atomics
        int rv[SC_ITEMS];
#pragma unroll
        for (int k = 0; k < SC_ITEMS; ++k)
            rv[k] = (gv[k] >= 0) ? atomicAdd(&lh[gv[k]], 1) : 0;
        __syncthreads();

        // phase 2: scan counts (2-wave shfl), reserve global spans
        if (t < BGRAPH) {
            const int val = lh[t];
            int xs = val;
            for (int off = 1; off < 64; off <<= 1) {
                const int y = __shfl_up(xs, off, 64);
                if ((t & 63) >= off) xs += y;
            }
            if ((t & 63) == 63) wtot[t >> 6] = xs;
            s_lofs[t] = xs - val;   // wave-local exclusive; fix wave1 below
        }
        __syncthreads();
        if (t < BGRAPH) {
            const int lofs = s_lofs[t] + ((t >= 64) ? wtot[0] : 0);
            s_lofs[t] = lofs;
            const int n = lh[t];
            const int gb = (n > 0) ? atomicAdd(&cursor[t * CURSOR_STRIDE], n) : 0;
            s_gbase[t] = t * CAP + gb - lofs;
        }
        __syncthreads();

        // phase 3: group ids into LDS
#pragma unroll
        for (int k = 0; k < SC_ITEMS; ++k) {
            if (gv[k] >= 0) {
                const int slot = s_lofs[gv[k]] + rv[k];
                s_ids[slot] = base0 + k * SC_THREADS + t;
                s_bin[slot] = (unsigned char)gv[k];
            }
        }
        __syncthreads();

        // phase 4: linear sweep -> coalesced global writes (runs per bin)
        for (int p = t; p < nval_blk; p += SC_THREADS) {
            const int b = s_bin[p];
            order[s_gbase[b] + p] = s_ids[p];
        }
    } else {
        // --- combined: precompute (v_e,c_e out; v_x,c_x local) + node agg ---
        const int g2  = blockIdx.x - nb_edge;   // 0..255
        const int g   = g2 >> 1;
        const int par = g2 & 1;                 // 0/1: row-stripe parity
        __shared__ float su[FDIM];
        __shared__ float sqe[HDIM];
        __shared__ float sqx[HDIM];
        __shared__ float s_vx[FDIM];
        __shared__ float s_cx;

        if (t < FDIM) su[t] = u[g * FDIM + t];
        __syncthreads();

        if (t < HDIM) {
            float acc = bq_e[t];
            for (int f = 0; f < FDIM; ++f) acc += su[f] * Wq_e[f * HDIM + t];
            sqe[t] = acc;
        } else if (t < 2 * HDIM) {
            const int h = t - HDIM;
            float acc = bq_x[h];
            for (int f = 0; f < FDIM; ++f) acc += su[f] * Wq_x[f * HDIM + h];
            sqx[h] = acc;
        }
        __syncthreads();

        if (t < FDIM) {
            float acce = 0.f, accx = 0.f;
            for (int h = 0; h < HDIM; ++h) {
                acce += Wk_e[t * HDIM + h] * sqe[h];
                accx += Wk_x[t * HDIM + h] * sqx[h];
            }
            if (par == 0) v_e[g * FDIM + t] = acce;   // idempotent; write once
            s_vx[t] = accx;
        }
        if (t == 0) {
            float cx = 0.f;
            for (int h = 0; h < HDIM; ++h) cx += bk_x[h] * sqx[h];
            s_cx = cx;
            if (par == 0) {
                float ce = 0.f;
                for (int h = 0; h < HDIM; ++h) ce += bk_e[h] * sqe[h];
                c_e[g] = ce;
            }
        }
        __syncthreads();

        // node aggregation for graph g (batch sorted -> contiguous range)
        int lo = 0, hi = N;
        while (lo < hi) { int mid = (lo + hi) >> 1; if (batch[mid] < g) lo = mid + 1; else hi = mid; }
        const int start = lo;
        hi = N;
        while (lo < hi) { int mid = (lo + hi) >> 1; if (batch[mid] < g + 1) lo = mid + 1; else hi = mid; }
        const int end = lo;

        const int hidx = t >> 5;          // 0..15 half-waves
        const int hl   = t & 31;
        const vf4 fv = *reinterpret_cast<const vf4*>(&s_vx[4 * hl]);
        const float cg = s_cx;

        vf4 acc = (vf4)(0.f);
        // depth-2 pipeline over rows start + 2*hidx + par, stride 32
        int row = start + 2 * hidx + par;
        vf4 fe = (vf4)(0.f);
        if (row < end) fe = ldnt4(x + (size_t)row * FDIM + 4 * hl);
        for (; row < end; row += 32) {
            vf4 fen = (vf4)(0.f);
            if (row + 32 < end) fen = ldnt4(x + (size_t)(row + 32) * FDIM + 4 * hl);
            float d = fe.x * fv.x + fe.y * fv.y + fe.z * fv.z + fe.w * fv.w;
            d += __shfl_xor(d, 1);
            d += __shfl_xor(d, 2);
            d += __shfl_xor(d, 4);
            d += __shfl_xor(d, 8);
            d += __shfl_xor(d, 16);
            const float a = 1.f / (1.f + __expf(-(d + cg)));
            acc.x += a * fe.x; acc.y += a * fe.y; acc.z += a * fe.z; acc.w += a * fe.w;
            fe = fen;
        }

        __shared__ float s_red[16][FDIM];
        s_red[hidx][4 * hl + 0] = acc.x;
        s_red[hidx][4 * hl + 1] = acc.y;
        s_red[hidx][4 * hl + 2] = acc.z;
        s_red[hidx][4 * hl + 3] = acc.w;
        __syncthreads();

        if (t < FDIM) {
            float ssum = 0.f;
#pragma unroll
            for (int k = 0; k < 16; ++k) ssum += s_red[k][t];
            unsafeAtomicAdd(&x_agg[g * FDIM + t], ssum);
        }
    }
}

// ---- edge aggregation + fused final GEMM (last-block per graph) ------------
__global__ __launch_bounds__(1024, 8) void agg_kernel(
    const float* __restrict__ e,      // [E,128]
    const int*   __restrict__ order,  // [B*CAP] grouped by graph
    const int*   __restrict__ cursor, // [B*CURSOR_STRIDE] = per-graph len
    const float* __restrict__ v_e, const float* __restrict__ c_e,
    float* __restrict__ e_agg,        // [B,128] pre-zeroed
    int* __restrict__ done,           // [B] pre-zeroed
    const float* __restrict__ x_agg,  // [B,128] complete (prep)
    const float* __restrict__ u,
    const float* __restrict__ Wu, const float* __restrict__ bu,
    float* __restrict__ out)          // [B,128]
{
    const int tid  = threadIdx.x;
    const int hidx = tid >> 5;
    const int hl   = tid & 31;
    __shared__ float s_red[32][FDIM];
    __shared__ int s_ids[MAXCHUNK];
    __shared__ int s_win;

    const int g = blockIdx.x / SLICES;
    const int s = blockIdx.x % SLICES;
    const int len = cursor[g * CURSOR_STRIDE];
    const int chunk = (len + SLICES - 1) / SLICES;
    const int clo = s * chunk;
    const int cnt = min(chunk, len - clo);   // may be <=0 for tail slices

    // coalesced preload of this slice's ids into LDS
    for (int i = tid; i < cnt; i += 1024) s_ids[i] = order[g * CAP + clo + i];
    __syncthreads();

    const vf4 fv = *reinterpret_cast<const vf4*>(v_e + g * FDIM + 4 * hl);
    const float cg = c_e[g];

    vf4 acc = (vf4)(0.f);

    // depth-3 row pipeline; ids come from LDS
    int p = hidx;
    vf4 f0 = (vf4)(0.f), f1 = (vf4)(0.f), f2 = (vf4)(0.f);
    if (p < cnt)      f0 = ldnt4(e + (size_t)s_ids[p]      * FDIM + 4 * hl);
    if (p + 32 < cnt) f1 = ldnt4(e + (size_t)s_ids[p + 32] * FDIM + 4 * hl);
    if (p + 64 < cnt) f2 = ldnt4(e + (size_t)s_ids[p + 64] * FDIM + 4 * hl);

    for (; p < cnt; p += 32) {
        vf4 f3 = (vf4)(0.f);
        if (p + 96 < cnt) f3 = ldnt4(e + (size_t)s_ids[p + 96] * FDIM + 4 * hl);

        float d = f0.x * fv.x + f0.y * fv.y + f0.z * fv.z + f0.w * fv.w;
        d += __shfl_xor(d, 1);
        d += __shfl_xor(d, 2);
        d += __shfl_xor(d, 4);
        d += __shfl_xor(d, 8);
        d += __shfl_xor(d, 16);
        const float a = 1.f / (1.f + __expf(-(d + cg)));
        acc.x += a * f0.x; acc.y += a * f0.y; acc.z += a * f0.z; acc.w += a * f0.w;

        f0 = f1; f1 = f2; f2 = f3;
    }

    s_red[hidx][4 * hl + 0] = acc.x;
    s_red[hidx][4 * hl + 1] = acc.y;
    s_red[hidx][4 * hl + 2] = acc.z;
    s_red[hidx][4 * hl + 3] = acc.w;
    __syncthreads();

    if (tid < FDIM) {
        float ssum = 0.f;
#pragma unroll
        for (int k = 0; k < 32; ++k) ssum += s_red[k][tid];
        unsafeAtomicAdd(&e_agg[g * FDIM + tid], ssum);
        __threadfence();   // make e_agg update visible device-wide
    }
    __syncthreads();

    if (tid == 0) {
        const int old = atomicAdd(&done[g], 1);
        s_win = (old == SLICES - 1) ? 1 : 0;
    }
    __syncthreads();

    if (s_win) {
        // last block for graph g: all e_agg[g] contributions visible.
        __shared__ float cat[3 * FDIM];
        if (tid < FDIM) {
            __threadfence();
            // device-scope coherent read (per-XCD L2s are not cross-coherent)
            cat[FDIM + tid] = __hip_atomic_load(&e_agg[g * FDIM + tid],
                                                __ATOMIC_RELAXED,
                                                __HIP_MEMORY_SCOPE_AGENT);
            cat[tid]            = x_agg[g * FDIM + tid];
            cat[2 * FDIM + tid] = u[g * FDIM + tid];
        }
        __syncthreads();
        if (tid < FDIM) {
            float acc2 = bu[tid];
#pragma unroll 8
            for (int r = 0; r < 3 * FDIM; ++r) acc2 += cat[r] * Wu[r * FDIM + tid];
            out[g * FDIM + tid] = acc2;
        }
    }
}

extern "C" void kernel_launch(void* const* d_in, const int* in_sizes, int n_in,
                              void* d_out, int out_size, void* d_ws, size_t ws_size,
                              hipStream_t stream) {
    const float* x          = (const float*)d_in[0];
    const float* e          = (const float*)d_in[1];
    const float* u          = (const float*)d_in[2];
    const int*   edge_index = (const int*)d_in[3];
    const int*   batch      = (const int*)d_in[4];
    const float* Wk_e = (const float*)d_in[5];
    const float* bk_e = (const float*)d_in[6];
    const float* Wq_e = (const float*)d_in[7];
    const float* bq_e = (const float*)d_in[8];
    const float* Wk_x = (const float*)d_in[9];
    const float* bk_x = (const float*)d_in[10];
    const float* Wq_x = (const float*)d_in[11];
    const float* bq_x = (const float*)d_in[12];
    const float* Wu   = (const float*)d_in[13];
    const float* bu   = (const float*)d_in[14];

    const int N = in_sizes[4];
    const int E = in_sizes[3] / 2;
    const int* src = edge_index;   // row 0 of (2,E)

    // workspace layout: e_agg | x_agg | cursor | done contiguous for ONE memset
    float* ws    = (float*)d_ws;
    float* v_e   = ws;                            // 16384
    float* c_e   = v_e + BGRAPH * FDIM;           // 128
    float* e_agg = c_e + BGRAPH;                  // 16384
    float* x_agg = e_agg + BGRAPH * FDIM;         // 16384
    int*   cursor = (int*)(x_agg + BGRAPH * FDIM);  // 128*16
    int*   done   = cursor + BGRAPH * CURSOR_STRIDE;// 128
    int*   order  = done + BGRAPH;                  // 128*CAP (8 MB)

    hipMemsetAsync(e_agg, 0,
        (2 * BGRAPH * FDIM + BGRAPH * CURSOR_STRIDE + BGRAPH) * sizeof(float),
        stream);

    const int nb_edge = (E + SC_TOTAL - 1) / SC_TOTAL;
    prep_kernel<<<nb_edge + 2 * BGRAPH, SC_THREADS, 0, stream>>>(
        src, batch, cursor, order, x_agg, x,
        u, Wk_e, bk_e, Wq_e, bq_e, Wk_x, bk_x, Wq_x, bq_x,
        v_e, c_e, E, N, nb_edge);

    agg_kernel<<<BGRAPH * SLICES, 1024, 0, stream>>>(
        e, order, cursor, v_e, c_e, e_agg, done, x_agg, u, Wu, bu,
        (float*)d_out);
}

// Round 13
// 197.863 us; speedup vs baseline: 3.3316x; 3.3316x over previous
//
#include <hip/hip_runtime.h>
#include <hip/hip_bf16.h>

// Sizes: N=100000, E=1600000, B=128, F=128, H=64.
// sigmoid(<e@Wk+bk, q_g>) = sigmoid(e . (Wk q_g) + bk.q_g)
//   => per-graph v[g] (128 floats) + scalar c[g].
//
// R11 -> R12: REVERT to R10 (196.8us). R11's last-block fused final used
// device-scope __threadfence() per block -> L2 writeback/invalidate storm
// across 4096 blocks -> agg 4x slower. Separate tiny final kernel is the
// right structure on multi-XCD CDNA4.

#define FDIM 128
#define BGRAPH 128
#define HDIM 64
#define SLICES 16
#define CAP 16384
#define CURSOR_STRIDE 16
#define SC_THREADS 512
#define SC_ITEMS 16          // 512*16 = 8192 edges per block
#define SC_TOTAL (SC_THREADS * SC_ITEMS)
#define MAXCHUNK (CAP / SLICES)   // 1024

typedef float vf4 __attribute__((ext_vector_type(4)));

__device__ inline vf4 ldnt4(const float* p) {
    return __builtin_nontemporal_load(reinterpret_cast<const vf4*>(p));
}

// ------- prep: edge binning blocks + (precompute + node agg) blocks --------
__global__ __launch_bounds__(SC_THREADS) void prep_kernel(
    const int* __restrict__ src, const int* __restrict__ batch,
    int* __restrict__ cursor,     // [B*CURSOR_STRIDE], pre-zeroed
    int* __restrict__ order,      // [B*CAP]
    float* __restrict__ x_agg,    // [B,128] pre-zeroed, atomically accumulated
    const float* __restrict__ x,  // [N,128]
    const float* __restrict__ u,
    const float* __restrict__ Wk_e, const float* __restrict__ bk_e,
    const float* __restrict__ Wq_e, const float* __restrict__ bq_e,
    const float* __restrict__ Wk_x, const float* __restrict__ bk_x,
    const float* __restrict__ Wq_x, const float* __restrict__ bq_x,
    float* __restrict__ v_e, float* __restrict__ c_e,
    int E, int N, int nb_edge)
{
    const int t = threadIdx.x;

    if (blockIdx.x < nb_edge) {
        // ------- edge binning: gid+rank -> LDS counting sort -> coalesced out ---
        __shared__ int lh[BGRAPH];            // counts
        __shared__ int s_lofs[BGRAPH];        // local exclusive offsets
        __shared__ int s_gbase[BGRAPH];       // g*CAP + gbase - lofs
        __shared__ int wtot[2];
        __shared__ int s_ids[SC_TOTAL];       // 32 KB grouped edge ids
        __shared__ unsigned char s_bin[SC_TOTAL]; // 8 KB bin tag per slot

        if (t < BGRAPH) lh[t] = 0;
        __syncthreads();

        const int base0 = blockIdx.x * SC_TOTAL;
        const int nval_blk = min(SC_TOTAL, E - base0);

        // phase 1a: src loads (independent)
        int iv[SC_ITEMS];
#pragma unroll
        for (int k = 0; k < SC_ITEMS; ++k) {
            const int i = base0 + k * SC_THREADS + t;
            iv[k] = (i < E) ? __builtin_nontemporal_load(src + i) : -1;
        }
        // phase 1b: batch gathers (independent; batch is L2-hot 400 KB)
        int gv[SC_ITEMS];
#pragma unroll
        for (int k = 0; k < SC_ITEMS; ++k)
            gv[k] = (iv[k] >= 0) ? batch[iv[k]] : -1;
        // phase 1c: rank atomics
        int rv[SC_ITEMS];
#pragma unroll
        for (int k = 0; k < SC_ITEMS; ++k)
            rv[k] = (gv[k] >= 0) ? atomicAdd(&lh[gv[k]], 1) : 0;
        __syncthreads();

        // phase 2: scan counts (2-wave shfl), reserve global spans
        if (t < BGRAPH) {
            const int val = lh[t];
            int xs = val;
            for (int off = 1; off < 64; off <<= 1) {
                const int y = __shfl_up(xs, off, 64);
                if ((t & 63) >= off) xs += y;
            }
            if ((t & 63) == 63) wtot[t >> 6] = xs;
            s_lofs[t] = xs - val;   // wave-local exclusive; fix wave1 below
        }
        __syncthreads();
        if (t < BGRAPH) {
            const int lofs = s_lofs[t] + ((t >= 64) ? wtot[0] : 0);
            s_lofs[t] = lofs;
            const int n = lh[t];
            const int gb = (n > 0) ? atomicAdd(&cursor[t * CURSOR_STRIDE], n) : 0;
            s_gbase[t] = t * CAP + gb - lofs;
        }
        __syncthreads();

        // phase 3: group ids into LDS
#pragma unroll
        for (int k = 0; k < SC_ITEMS; ++k) {
            if (gv[k] >= 0) {
                const int slot = s_lofs[gv[k]] + rv[k];
                s_ids[slot] = base0 + k * SC_THREADS + t;
                s_bin[slot] = (unsigned char)gv[k];
            }
        }
        __syncthreads();

        // phase 4: linear sweep -> coalesced global writes (runs per bin)
        for (int p = t; p < nval_blk; p += SC_THREADS) {
            const int b = s_bin[p];
            order[s_gbase[b] + p] = s_ids[p];
        }
    } else {
        // --- combined: precompute (v_e,c_e out; v_x,c_x local) + node agg ---
        const int g2  = blockIdx.x - nb_edge;   // 0..255
        const int g   = g2 >> 1;
        const int par = g2 & 1;                 // 0/1: row-stripe parity
        __shared__ float su[FDIM];
        __shared__ float sqe[HDIM];
        __shared__ float sqx[HDIM];
        __shared__ float s_vx[FDIM];
        __shared__ float s_cx;

        if (t < FDIM) su[t] = u[g * FDIM + t];
        __syncthreads();

        if (t < HDIM) {
            float acc = bq_e[t];
            for (int f = 0; f < FDIM; ++f) acc += su[f] * Wq_e[f * HDIM + t];
            sqe[t] = acc;
        } else if (t < 2 * HDIM) {
            const int h = t - HDIM;
            float acc = bq_x[h];
            for (int f = 0; f < FDIM; ++f) acc += su[f] * Wq_x[f * HDIM + h];
            sqx[h] = acc;
        }
        __syncthreads();

        if (t < FDIM) {
            float acce = 0.f, accx = 0.f;
            for (int h = 0; h < HDIM; ++h) {
                acce += Wk_e[t * HDIM + h] * sqe[h];
                accx += Wk_x[t * HDIM + h] * sqx[h];
            }
            if (par == 0) v_e[g * FDIM + t] = acce;   // idempotent; write once
            s_vx[t] = accx;
        }
        if (t == 0) {
            float cx = 0.f;
            for (int h = 0; h < HDIM; ++h) cx += bk_x[h] * sqx[h];
            s_cx = cx;
            if (par == 0) {
                float ce = 0.f;
                for (int h = 0; h < HDIM; ++h) ce += bk_e[h] * sqe[h];
                c_e[g] = ce;
            }
        }
        __syncthreads();

        // node aggregation for graph g (batch sorted -> contiguous range)
        int lo = 0, hi = N;
        while (lo < hi) { int mid = (lo + hi) >> 1; if (batch[mid] < g) lo = mid + 1; else hi = mid; }
        const int start = lo;
        hi = N;
        while (lo < hi) { int mid = (lo + hi) >> 1; if (batch[mid] < g + 1) lo = mid + 1; else hi = mid; }
        const int end = lo;

        const int hidx = t >> 5;          // 0..15 half-waves
        const int hl   = t & 31;
        const vf4 fv = *reinterpret_cast<const vf4*>(&s_vx[4 * hl]);
        const float cg = s_cx;

        vf4 acc = (vf4)(0.f);
        // depth-2 pipeline over rows start + 2*hidx + par, stride 32
        int row = start + 2 * hidx + par;
        vf4 fe = (vf4)(0.f);
        if (row < end) fe = ldnt4(x + (size_t)row * FDIM + 4 * hl);
        for (; row < end; row += 32) {
            vf4 fen = (vf4)(0.f);
            if (row + 32 < end) fen = ldnt4(x + (size_t)(row + 32) * FDIM + 4 * hl);
            float d = fe.x * fv.x + fe.y * fv.y + fe.z * fv.z + fe.w * fv.w;
            d += __shfl_xor(d, 1);
            d += __shfl_xor(d, 2);
            d += __shfl_xor(d, 4);
            d += __shfl_xor(d, 8);
            d += __shfl_xor(d, 16);
            const float a = 1.f / (1.f + __expf(-(d + cg)));
            acc.x += a * fe.x; acc.y += a * fe.y; acc.z += a * fe.z; acc.w += a * fe.w;
            fe = fen;
        }

        __shared__ float s_red[16][FDIM];
        s_red[hidx][4 * hl + 0] = acc.x;
        s_red[hidx][4 * hl + 1] = acc.y;
        s_red[hidx][4 * hl + 2] = acc.z;
        s_red[hidx][4 * hl + 3] = acc.w;
        __syncthreads();

        if (t < FDIM) {
            float ssum = 0.f;
#pragma unroll
            for (int k = 0; k < 16; ++k) ssum += s_red[k][t];
            unsafeAtomicAdd(&x_agg[g * FDIM + t], ssum);
        }
    }
}

// ---------------- edge aggregation: block per (graph, slice) ----------------
__global__ __launch_bounds__(1024, 8) void agg_kernel(
    const float* __restrict__ e,      // [E,128]
    const int*   __restrict__ order,  // [B*CAP] grouped by graph
    const int*   __restrict__ cursor, // [B*CURSOR_STRIDE] = per-graph len
    const float* __restrict__ v_e, const float* __restrict__ c_e,
    float* __restrict__ e_agg)        // [B,128] pre-zeroed
{
    const int tid  = threadIdx.x;
    const int hidx = tid >> 5;
    const int hl   = tid & 31;
    __shared__ float s_red[32][FDIM];
    __shared__ int s_ids[MAXCHUNK];

    const int g = blockIdx.x / SLICES;
    const int s = blockIdx.x % SLICES;
    const int len = cursor[g * CURSOR_STRIDE];
    const int chunk = (len + SLICES - 1) / SLICES;
    const int clo = s * chunk;
    const int cnt = min(chunk, len - clo);   // may be <=0 for tail slices

    // coalesced preload of this slice's ids into LDS
    for (int i = tid; i < cnt; i += 1024) s_ids[i] = order[g * CAP + clo + i];
    __syncthreads();

    const vf4 fv = *reinterpret_cast<const vf4*>(v_e + g * FDIM + 4 * hl);
    const float cg = c_e[g];

    vf4 acc = (vf4)(0.f);

    // depth-3 row pipeline; ids come from LDS
    int p = hidx;
    vf4 f0 = (vf4)(0.f), f1 = (vf4)(0.f), f2 = (vf4)(0.f);
    if (p < cnt)      f0 = ldnt4(e + (size_t)s_ids[p]      * FDIM + 4 * hl);
    if (p + 32 < cnt) f1 = ldnt4(e + (size_t)s_ids[p + 32] * FDIM + 4 * hl);
    if (p + 64 < cnt) f2 = ldnt4(e + (size_t)s_ids[p + 64] * FDIM + 4 * hl);

    for (; p < cnt; p += 32) {
        vf4 f3 = (vf4)(0.f);
        if (p + 96 < cnt) f3 = ldnt4(e + (size_t)s_ids[p + 96] * FDIM + 4 * hl);

        float d = f0.x * fv.x + f0.y * fv.y + f0.z * fv.z + f0.w * fv.w;
        d += __shfl_xor(d, 1);
        d += __shfl_xor(d, 2);
        d += __shfl_xor(d, 4);
        d += __shfl_xor(d, 8);
        d += __shfl_xor(d, 16);
        const float a = 1.f / (1.f + __expf(-(d + cg)));
        acc.x += a * f0.x; acc.y += a * f0.y; acc.z += a * f0.z; acc.w += a * f0.w;

        f0 = f1; f1 = f2; f2 = f3;
    }

    s_red[hidx][4 * hl + 0] = acc.x;
    s_red[hidx][4 * hl + 1] = acc.y;
    s_red[hidx][4 * hl + 2] = acc.z;
    s_red[hidx][4 * hl + 3] = acc.w;
    __syncthreads();

    if (tid < FDIM) {
        float ssum = 0.f;
#pragma unroll
        for (int k = 0; k < 32; ++k) ssum += s_red[k][tid];
        unsafeAtomicAdd(&e_agg[g * FDIM + tid], ssum);
    }
}

// ---------------- final tiny GEMM ----------------
__global__ __launch_bounds__(128) void final_kernel(
    const float* __restrict__ x_agg, const float* __restrict__ e_agg,
    const float* __restrict__ u,
    const float* __restrict__ Wu, const float* __restrict__ bu,
    float* __restrict__ out)
{
    const int g = blockIdx.x;
    const int o = threadIdx.x;
    __shared__ float cat[3 * FDIM];
    cat[o]            = x_agg[g * FDIM + o];
    cat[FDIM + o]     = e_agg[g * FDIM + o];
    cat[2 * FDIM + o] = u[g * FDIM + o];
    __syncthreads();

    float acc = bu[o];
#pragma unroll 8
    for (int r = 0; r < 3 * FDIM; ++r) acc += cat[r] * Wu[r * FDIM + o];
    out[g * FDIM + o] = acc;
}

extern "C" void kernel_launch(void* const* d_in, const int* in_sizes, int n_in,
                              void* d_out, int out_size, void* d_ws, size_t ws_size,
                              hipStream_t stream) {
    const float* x          = (const float*)d_in[0];
    const float* e          = (const float*)d_in[1];
    const float* u          = (const float*)d_in[2];
    const int*   edge_index = (const int*)d_in[3];
    const int*   batch      = (const int*)d_in[4];
    const float* Wk_e = (const float*)d_in[5];
    const float* bk_e = (const float*)d_in[6];
    const float* Wq_e = (const float*)d_in[7];
    const float* bq_e = (const float*)d_in[8];
    const float* Wk_x = (const float*)d_in[9];
    const float* bk_x = (const float*)d_in[10];
    const float* Wq_x = (const float*)d_in[11];
    const float* bq_x = (const float*)d_in[12];
    const float* Wu   = (const float*)d_in[13];
    const float* bu   = (const float*)d_in[14];

    const int N = in_sizes[4];
    const int E = in_sizes[3] / 2;
    const int* src = edge_index;   // row 0 of (2,E)

    // workspace layout: e_agg | x_agg | cursor contiguous for ONE memset
    float* ws    = (float*)d_ws;
    float* v_e   = ws;                            // 16384
    float* c_e   = v_e + BGRAPH * FDIM;           // 128
    float* e_agg = c_e + BGRAPH;                  // 16384
    float* x_agg = e_agg + BGRAPH * FDIM;         // 16384
    int*   cursor = (int*)(x_agg + BGRAPH * FDIM);  // 128*16
    int*   order  = cursor + BGRAPH * CURSOR_STRIDE;// 128*CAP (8 MB)

    hipMemsetAsync(e_agg, 0,
        (2 * BGRAPH * FDIM + BGRAPH * CURSOR_STRIDE) * sizeof(float), stream);

    const int nb_edge = (E + SC_TOTAL - 1) / SC_TOTAL;
    prep_kernel<<<nb_edge + 2 * BGRAPH, SC_THREADS, 0, stream>>>(
        src, batch, cursor, order, x_agg, x,
        u, Wk_e, bk_e, Wq_e, bq_e, Wk_x, bk_x, Wq_x, bq_x,
        v_e, c_e, E, N, nb_edge);

    agg_kernel<<<BGRAPH * SLICES, 1024, 0, stream>>>(
        e, order, cursor, v_e, c_e, e_agg);

    final_kernel<<<BGRAPH, 128, 0, stream>>>(
        x_agg, e_agg, u, Wu, bu, (float*)d_out);
}